// Round 13
// baseline (1127.519 us; speedup 1.0000x reference)
//
#include <hip/hip_runtime.h>

#define Bn 64
#define Sn 512
#define Hn 1024
#define Tn 67

#define LOG2E 1.4426950408889634f
#define LN2   0.6931471805599453f

// ---------------------------------------------------------------------------
// Kernel 1: em = leaky_relu(hidden, 0.01) @ W + b  (unchanged, frozen)
// ---------------------------------------------------------------------------
__global__ __launch_bounds__(256) void gemm_em(
    const float* __restrict__ hidden, const float* __restrict__ W,
    const float* __restrict__ bias, float* __restrict__ em,
    float* __restrict__ out)
{
    __shared__ __align__(16) float hs[64][36];
    __shared__ __align__(16) float wt[80][36];

    const int tid = threadIdx.x;
    const int tx = tid & 15, ty = tid >> 4;
    const int row0 = blockIdx.x * 64;

    if (blockIdx.x == 0 && tid == 0) out[0] = 0.0f;

    float acc[4][5];
#pragma unroll
    for (int u = 0; u < 4; ++u)
#pragma unroll
        for (int v = 0; v < 5; ++v) acc[u][v] = 0.f;

    for (int kc = 0; kc < Hn; kc += 32) {
#pragma unroll
        for (int l = 0; l < 2; ++l) {
            int idx = tid + l * 256;
            int r = idx >> 3, kq = (idx & 7) << 2;
            float4 v = *reinterpret_cast<const float4*>(
                &hidden[(size_t)(row0 + r) * Hn + kc + kq]);
            v.x = v.x > 0.f ? v.x : 0.01f * v.x;
            v.y = v.y > 0.f ? v.y : 0.01f * v.y;
            v.z = v.z > 0.f ? v.z : 0.01f * v.z;
            v.w = v.w > 0.f ? v.w : 0.01f * v.w;
            *reinterpret_cast<float4*>(&hs[r][kq]) = v;
        }
        for (int idx = tid; idx < 32 * Tn; idx += 256) {
            int k = idx / Tn;
            int t = idx - k * Tn;
            wt[t][k] = W[(size_t)(kc + k) * Tn + t];
        }
        __syncthreads();

#pragma unroll
        for (int k0 = 0; k0 < 32; k0 += 4) {
            float4 hv[4], wv[5];
#pragma unroll
            for (int u = 0; u < 4; ++u)
                hv[u] = *reinterpret_cast<float4*>(&hs[ty + 16 * u][k0]);
#pragma unroll
            for (int v = 0; v < 5; ++v)
                wv[v] = *reinterpret_cast<float4*>(&wt[tx + 16 * v][k0]);
#pragma unroll
            for (int u = 0; u < 4; ++u)
#pragma unroll
                for (int v = 0; v < 5; ++v) {
                    acc[u][v] = fmaf(hv[u].x, wv[v].x, acc[u][v]);
                    acc[u][v] = fmaf(hv[u].y, wv[v].y, acc[u][v]);
                    acc[u][v] = fmaf(hv[u].z, wv[v].z, acc[u][v]);
                    acc[u][v] = fmaf(hv[u].w, wv[v].w, acc[u][v]);
                }
        }
        __syncthreads();
    }

#pragma unroll
    for (int v = 0; v < 5; ++v) {
        int c = tx + 16 * v;
        if (c < Tn) {
            float bb = bias[c];
#pragma unroll
            for (int u = 0; u < 4; ++u) {
                int row = row0 + ty + 16 * u;
                em[(size_t)row * Tn + c] = acc[u][v] + bb;
            }
        }
    }
}

// 68-name expander
#define R67(X) X(0) X(1) X(2) X(3) X(4) X(5) X(6) X(7) X(8) X(9) \
 X(10) X(11) X(12) X(13) X(14) X(15) X(16) X(17) X(18) X(19) \
 X(20) X(21) X(22) X(23) X(24) X(25) X(26) X(27) X(28) X(29) \
 X(30) X(31) X(32) X(33) X(34) X(35) X(36) X(37) X(38) X(39) \
 X(40) X(41) X(42) X(43) X(44) X(45) X(46) X(47) X(48) X(49) \
 X(50) X(51) X(52) X(53) X(54) X(55) X(56) X(57) X(58) X(59) \
 X(60) X(61) X(62) X(63) X(64) X(65) X(66)

// ---------------------------------------------------------------------------
// Kernel 2: 128 blocks x 64 threads. ONE wave per scan chain, one chain/CU.
// blocks 0-63: CRF (+numerator+loss); blocks 64-127: Viterbi (+backtrace).
// Transition tables in 68 NAMED VGPRs. LDS only for the 68-state broadcast,
// extras arrays, hist. No __syncthreads anywhere (single wave per block).
// ---------------------------------------------------------------------------
__global__ __launch_bounds__(64, 1) void crf_scan9(
    const float* __restrict__ em, const int* __restrict__ labels,
    const int* __restrict__ mask, const float* __restrict__ startT,
    const float* __restrict__ endT, const float* __restrict__ trans,
    float* __restrict__ out)
{
    __shared__ __align__(16) float pst[2][72];   // state (+CRF slots 68,69)
    __shared__ __align__(16) float gA[3][72];    // extras contributions/cands
    __shared__ __align__(16) float g2v[3][16];
    __shared__ __align__(16) int   g2i[3][16];
    __shared__ unsigned char hist[Sn - 1][68];
    __shared__ int tg[Sn];

    const int lane = threadIdx.x;
    const bool isV = blockIdx.x >= 64;
    const int b = blockIdx.x & 63;
    const float* emg = em + (size_t)b * Sn * Tn;
    const int* mg = mask + b * Sn;
    const int u2 = lane < 3 ? lane : 2;
    const int st2 = 64 + u2;
    const int rsec = (lane < 3) ? (64 + lane) : 0;

    if (!isV) {
        // ======================= CRF block =======================
#define CE(i) float e##i = exp2f(trans[(i) * Tn + lane] * LOG2E);
        R67(CE)
#undef CE
        float Es0 = exp2f(trans[lane * Tn + 64] * LOG2E);
        float Es1 = exp2f(trans[lane * Tn + 65] * LOG2E);
        float Es2 = exp2f(trans[lane * Tn + 66] * LOG2E);
        float Et0 = exp2f(trans[rsec * Tn + 64] * LOG2E);
        float Et1 = exp2f(trans[rsec * Tn + 65] * LOG2E);
        float Et2 = exp2f(trans[rsec * Tn + 66] * LOG2E);

        if (lane == 0) {
            pst[0][67] = 0.f; pst[1][67] = 0.f;
            gA[0][67] = 0.f; gA[1][67] = 0.f; gA[2][67] = 0.f;
        }

        float sc1 = startT[lane] + emg[lane];
        float sc2 = startT[st2] + emg[st2];
        float Mn = startT[0] + emg[0];             // uniform
        float p1 = exp2f((sc1 - Mn) * LOG2E);
        float p2 = exp2f((sc2 - Mn) * LOG2E);
        pst[0][lane] = p1;
        if (lane < 3) pst[0][64 + lane] = p2;
        if (lane == 0) { pst[0][68] = sc1; pst[0][69] = Mn; }
        gA[0][lane] = p1 * Es0; gA[1][lane] = p1 * Es1; gA[2][lane] = p1 * Es2;
        if (lane < 3) {
            gA[0][64 + lane] = p2 * Et0;
            gA[1][64 + lane] = p2 * Et1;
            gA[2][64 + lane] = p2 * Et2;
        }

        float emn1 = emg[Tn + lane], emn2 = emg[Tn + st2];
        int mn = mg[1];

        for (int t = 1; t < Sn; ++t) {
            float emc1 = emn1, emc2 = emn2;
            int m = mn;
            if (t + 1 < Sn) {
                emn1 = emg[(size_t)(t + 1) * Tn + lane];
                emn2 = emg[(size_t)(t + 1) * Tn + st2];
                mn = mg[t + 1];
            }
            const int pv = (t + 1) & 1, cu = t & 1;
            const float4* P4 = (const float4*)&pst[pv][0];
            float Mu = pst[pv][69];
            float sc0p = pst[pv][68];
            float a0 = 0, a1 = 0, a2 = 0, a3 = 0;
#define DQ(q, i0, i1, i2, i3) { float4 pq = P4[q]; \
            a0 = fmaf(pq.x, e##i0, a0); a1 = fmaf(pq.y, e##i1, a1); \
            a2 = fmaf(pq.z, e##i2, a2); a3 = fmaf(pq.w, e##i3, a3); }
            DQ(0,0,1,2,3) DQ(1,4,5,6,7) DQ(2,8,9,10,11) DQ(3,12,13,14,15)
            DQ(4,16,17,18,19) DQ(5,20,21,22,23) DQ(6,24,25,26,27)
            DQ(7,28,29,30,31) DQ(8,32,33,34,35) DQ(9,36,37,38,39)
            DQ(10,40,41,42,43) DQ(11,44,45,46,47) DQ(12,48,49,50,51)
            DQ(13,52,53,54,55) DQ(14,56,57,58,59) DQ(15,60,61,62,63)
            { float4 pq = P4[16];
              a0 = fmaf(pq.x, e64, a0); a1 = fmaf(pq.y, e65, a1);
              a2 = fmaf(pq.z, e66, a2); }
#undef DQ
            float s1 = (a0 + a1) + (a2 + a3);

            float s2 = 0.f;
            if (lane < 3) {
                const float4* G4 = (const float4*)&gA[u2][0];
                float b0 = 0, b1 = 0, b2 = 0, b3 = 0;
#pragma unroll
                for (int q = 0; q < 17; ++q) {
                    float4 gv = G4[q];
                    b0 += gv.x; b1 += gv.y; b2 += gv.z; b3 += gv.w;
                }
                s2 = (b0 + b1) + (b2 + b3);
            }
            float n1 = Mu + log2f(s1) * LN2 + emc1;
            float n2 = Mu + log2f(s2) * LN2 + emc2;
            if (m) { sc1 = n1; sc2 = n2; }
            Mn = sc0p;
            p1 = exp2f((sc1 - Mn) * LOG2E);
            p2 = exp2f((sc2 - Mn) * LOG2E);
            pst[cu][lane] = p1;
            if (lane < 3) pst[cu][64 + lane] = p2;
            if (lane == 0) { pst[cu][68] = sc1; pst[cu][69] = Mn; }
            gA[0][lane] = p1 * Es0; gA[1][lane] = p1 * Es1; gA[2][lane] = p1 * Es2;
            if (lane < 3) {
                gA[0][64 + lane] = p2 * Et0;
                gA[1][64 + lane] = p2 * Et1;
                gA[2][64 + lane] = p2 * Et2;
            }
        }

        // ---- denominator ----
        float* F = &pst[0][0];
        F[lane] = sc1 + endT[lane];
        if (lane < 3) F[64 + lane] = sc2 + endT[64 + lane];
        if (lane == 0) F[67] = -1e30f;
        const float4* Fv = (const float4*)F;
        float mx = -1e30f;
#pragma unroll
        for (int q = 0; q < 17; ++q) {
            float4 v = Fv[q];
            mx = fmaxf(mx, fmaxf(fmaxf(v.x, v.y), fmaxf(v.z, v.w)));
        }
        float ss = 0.f;
#pragma unroll
        for (int q = 0; q < 17; ++q) {
            float4 v = Fv[q];
            ss += exp2f((v.x - mx) * LOG2E) + exp2f((v.y - mx) * LOG2E)
                + exp2f((v.z - mx) * LOG2E) + exp2f((v.w - mx) * LOG2E);
        }
        float denom = mx + log2f(ss) * LN2;

        // ---- numerator (in-wave) ----
        float part = 0.f; int lenp = 0;
#pragma unroll
        for (int i = 0; i < 8; ++i) {
            int s = lane + i * 64;
            int ms = mg[s];
            lenp += ms;
            int ls = labels[b * Sn + s];
            if (s == 0) {
                part += startT[ls] + emg[ls];
            } else if (ms) {
                int lp = labels[b * Sn + s - 1];
                part += trans[lp * Tn + ls] + emg[(size_t)s * Tn + ls];
            }
        }
#pragma unroll
        for (int k = 1; k < 64; k <<= 1) {
            part += __shfl_xor(part, k);
            lenp += __shfl_xor(lenp, k);
        }
        if (lane == 0) {
            int last = labels[b * Sn + lenp - 1];
            float num = part + endT[last];
            atomicAdd(out, -(num - denom) * (1.0f / (float)Bn));
        }
    } else {
        // ======================= Viterbi block =======================
#define CT(i) float t##i = trans[(i) * Tn + lane];
        R67(CT)
#undef CT
        float t67 = -1e30f;
        float Tf0 = trans[lane * Tn + 64];
        float Tf1 = trans[lane * Tn + 65];
        float Tf2 = trans[lane * Tn + 66];
        float Tt0 = trans[rsec * Tn + 64];
        float Tt1 = trans[rsec * Tn + 65];
        float Tt2 = trans[rsec * Tn + 66];

        if (lane == 0) {
            pst[0][67] = -1e30f; pst[1][67] = -1e30f;
            gA[0][67] = -1e30f; gA[1][67] = -1e30f; gA[2][67] = -1e30f;
        }

        float sc1 = startT[lane] + emg[lane];
        float sc2 = startT[st2] + emg[st2];
        pst[0][lane] = sc1;
        if (lane < 3) pst[0][64 + lane] = sc2;
        gA[0][lane] = sc1 + Tf0; gA[1][lane] = sc1 + Tf1; gA[2][lane] = sc1 + Tf2;
        if (lane < 3) {
            gA[0][64 + lane] = sc2 + Tt0;
            gA[1][64 + lane] = sc2 + Tt1;
            gA[2][64 + lane] = sc2 + Tt2;
        }

        float emn1 = emg[Tn + lane], emn2 = emg[Tn + st2];
        int mn = mg[1];

        for (int t = 1; t < Sn; ++t) {
            float emc1 = emn1, emc2 = emn2;
            int m = mn;
            if (t + 1 < Sn) {
                emn1 = emg[(size_t)(t + 1) * Tn + lane];
                emn2 = emg[(size_t)(t + 1) * Tn + st2];
                mn = mg[t + 1];
            }
            const int pv = (t + 1) & 1, cu = t & 1;

            // stage1 of extras: 48 lanes quad-reduce gA
            if (lane < 48) {
                int su = lane >> 4, si = lane & 15;
                float4 gq = *(const float4*)&gA[su][4 * si];
                float gm = fmaxf(fmaxf(gq.x, gq.y), fmaxf(gq.z, gq.w));
                int gs = (gq.x == gm) ? 0 : ((gq.y == gm) ? 1 : ((gq.z == gm) ? 2 : 3));
                g2v[su][si] = gm;
                g2i[su][si] = 4 * si + gs;
            }

            // primary tournament (named regs)
            const float4* V4 = (const float4*)&pst[pv][0];
#define VQ(q, i0, i1, i2, i3) float mq##q; int sq##q; { float4 v = V4[q]; \
            float c0 = v.x + t##i0, c1 = v.y + t##i1, c2 = v.z + t##i2, c3 = v.w + t##i3; \
            mq##q = fmaxf(fmaxf(c0, c1), fmaxf(c2, c3)); \
            sq##q = (c0 == mq##q) ? 0 : ((c1 == mq##q) ? 1 : ((c2 == mq##q) ? 2 : 3)); }
            VQ(0,0,1,2,3) VQ(1,4,5,6,7) VQ(2,8,9,10,11) VQ(3,12,13,14,15)
            VQ(4,16,17,18,19) VQ(5,20,21,22,23) VQ(6,24,25,26,27)
            VQ(7,28,29,30,31) VQ(8,32,33,34,35) VQ(9,36,37,38,39)
            VQ(10,40,41,42,43) VQ(11,44,45,46,47) VQ(12,48,49,50,51)
            VQ(13,52,53,54,55) VQ(14,56,57,58,59) VQ(15,60,61,62,63)
            VQ(16,64,65,66,67)
#undef VQ
            float y0 = fmaxf(mq0, mq1), y1 = fmaxf(mq2, mq3);
            float y2 = fmaxf(mq4, mq5), y3 = fmaxf(mq6, mq7);
            float y4 = fmaxf(mq8, mq9), y5 = fmaxf(mq10, mq11);
            float y6 = fmaxf(mq12, mq13), y7 = fmaxf(mq14, mq15);
            y0 = fmaxf(y0, y1); y2 = fmaxf(y2, y3);
            y4 = fmaxf(y4, y5); y6 = fmaxf(y6, y7);
            y0 = fmaxf(y0, y2); y4 = fmaxf(y4, y6);
            float m1 = fmaxf(fmaxf(y0, y4), mq16);
#define FS(q) int fs##q = (mq##q == m1) ? (4 * q + sq##q) : 1023;
            FS(0) FS(1) FS(2) FS(3) FS(4) FS(5) FS(6) FS(7) FS(8)
            FS(9) FS(10) FS(11) FS(12) FS(13) FS(14) FS(15) FS(16)
#undef FS
            int x0 = min(fs0, fs1), x1 = min(fs2, fs3);
            int x2 = min(fs4, fs5), x3 = min(fs6, fs7);
            int x4 = min(fs8, fs9), x5 = min(fs10, fs11);
            int x6 = min(fs12, fs13), x7 = min(fs14, fs15);
            x0 = min(x0, x1); x2 = min(x2, x3);
            x4 = min(x4, x5); x6 = min(x6, x7);
            x0 = min(x0, x2); x4 = min(x4, x6);
            int idxp = min(min(x0, x4), fs16);

            // stage2 of extras: lanes 0-2 stream 16 partials + 3 tail cands
            float n2 = 0.f; int bi2 = 0;
            if (lane < 3) {
                const float4* Gv = (const float4*)&g2v[u2][0];
                const int4* Gi = (const int4*)&g2i[u2][0];
                float4 va = Gv[0], vb = Gv[1], vc = Gv[2], vd = Gv[3];
                int4 ia = Gi[0], ib = Gi[1], ic = Gi[2], id = Gi[3];
                float bv = va.x; int bi = ia.x;
                if (va.y > bv) { bv = va.y; bi = ia.y; }
                if (va.z > bv) { bv = va.z; bi = ia.z; }
                if (va.w > bv) { bv = va.w; bi = ia.w; }
                if (vb.x > bv) { bv = vb.x; bi = ib.x; }
                if (vb.y > bv) { bv = vb.y; bi = ib.y; }
                if (vb.z > bv) { bv = vb.z; bi = ib.z; }
                if (vb.w > bv) { bv = vb.w; bi = ib.w; }
                if (vc.x > bv) { bv = vc.x; bi = ic.x; }
                if (vc.y > bv) { bv = vc.y; bi = ic.y; }
                if (vc.z > bv) { bv = vc.z; bi = ic.z; }
                if (vc.w > bv) { bv = vc.w; bi = ic.w; }
                if (vd.x > bv) { bv = vd.x; bi = id.x; }
                if (vd.y > bv) { bv = vd.y; bi = id.y; }
                if (vd.z > bv) { bv = vd.z; bi = id.z; }
                if (vd.w > bv) { bv = vd.w; bi = id.w; }
                float4 ge = *(const float4*)&gA[u2][64];
                if (ge.x > bv) { bv = ge.x; bi = 64; }
                if (ge.y > bv) { bv = ge.y; bi = 65; }
                if (ge.z > bv) { bv = ge.z; bi = 66; }
                n2 = bv + emc2; bi2 = bi;
            }

            float n1 = m1 + emc1;
            int idx1 = m ? idxp : lane;
            int idx2 = m ? bi2 : st2;
            if (m) { sc1 = n1; sc2 = n2; }

            hist[t - 1][lane] = (unsigned char)idx1;
            pst[cu][lane] = sc1;
            if (lane < 3) {
                hist[t - 1][64 + lane] = (unsigned char)idx2;
                pst[cu][64 + lane] = sc2;
            }
            gA[0][lane] = sc1 + Tf0; gA[1][lane] = sc1 + Tf1; gA[2][lane] = sc1 + Tf2;
            if (lane < 3) {
                gA[0][64 + lane] = sc2 + Tt0;
                gA[1][64 + lane] = sc2 + Tt1;
                gA[2][64 + lane] = sc2 + Tt2;
            }
        }

        // ---- final argmax over sc + endT (first index) ----
        float* F = &pst[0][0];
        F[lane] = sc1 + endT[lane];
        if (lane < 3) F[64 + lane] = sc2 + endT[64 + lane];
        if (lane == 0) F[67] = -1e30f;
        const float4* Fv = (const float4*)F;
#define WQ(q) float wq##q; int wsq##q; { float4 v = Fv[q]; \
        wq##q = fmaxf(fmaxf(v.x, v.y), fmaxf(v.z, v.w)); \
        wsq##q = (v.x == wq##q) ? 0 : ((v.y == wq##q) ? 1 : ((v.z == wq##q) ? 2 : 3)); }
        WQ(0) WQ(1) WQ(2) WQ(3) WQ(4) WQ(5) WQ(6) WQ(7) WQ(8)
        WQ(9) WQ(10) WQ(11) WQ(12) WQ(13) WQ(14) WQ(15) WQ(16)
#undef WQ
        float z0 = fmaxf(wq0, wq1), z1 = fmaxf(wq2, wq3);
        float z2 = fmaxf(wq4, wq5), z3 = fmaxf(wq6, wq7);
        float z4 = fmaxf(wq8, wq9), z5 = fmaxf(wq10, wq11);
        float z6 = fmaxf(wq12, wq13), z7 = fmaxf(wq14, wq15);
        z0 = fmaxf(z0, z1); z2 = fmaxf(z2, z3);
        z4 = fmaxf(z4, z5); z6 = fmaxf(z6, z7);
        z0 = fmaxf(z0, z2); z4 = fmaxf(z4, z6);
        float mF = fmaxf(fmaxf(z0, z4), wq16);
#define GS(q) int gs##q = (wq##q == mF) ? (4 * q + wsq##q) : 1023;
        GS(0) GS(1) GS(2) GS(3) GS(4) GS(5) GS(6) GS(7) GS(8)
        GS(9) GS(10) GS(11) GS(12) GS(13) GS(14) GS(15) GS(16)
#undef GS
        int w0 = min(gs0, gs1), w1 = min(gs2, gs3);
        int w2 = min(gs4, gs5), w3 = min(gs6, gs7);
        int w4 = min(gs8, gs9), w5 = min(gs10, gs11);
        int w6 = min(gs12, gs13), w7 = min(gs14, gs15);
        w0 = min(w0, w1); w2 = min(w2, w3);
        w4 = min(w4, w5); w6 = min(w6, w7);
        w0 = min(w0, w2); w4 = min(w4, w6);
        int best = min(min(w0, w4), gs16);

        if (lane == 0) {
            int carry = best;
            tg[Sn - 1] = carry;
            for (int k = Sn - 2; k >= 0; --k) {
                carry = hist[k][carry];
                tg[k] = carry;
            }
        }
        // wave-uniform availability: lane0's tg writes complete in-order;
        // other lanes must see them -> single wave, in-order LDS ensures it.
        float* tagsOut = out + 1 + b * Sn;
#pragma unroll
        for (int i = 0; i < 8; ++i) {
            int s = lane + i * 64;
            tagsOut[s] = mg[s] ? (float)tg[s] : 0.f;
        }
    }
}

extern "C" void kernel_launch(void* const* d_in, const int* in_sizes, int n_in,
                              void* d_out, int out_size, void* d_ws, size_t ws_size,
                              hipStream_t stream) {
    const float* hidden = (const float*)d_in[0];
    const int*   labels = (const int*)d_in[1];
    const int*   maskp  = (const int*)d_in[2];
    const float* W      = (const float*)d_in[3];
    const float* bias   = (const float*)d_in[4];
    const float* startT = (const float*)d_in[5];
    const float* endT   = (const float*)d_in[6];
    const float* trans  = (const float*)d_in[7];
    float* out = (float*)d_out;
    float* em  = out + 1 + (size_t)Bn * Sn;

    hipLaunchKernelGGL(gemm_em, dim3((Bn * Sn) / 64), dim3(256), 0, stream,
                       hidden, W, bias, em, out);
    hipLaunchKernelGGL(crf_scan9, dim3(2 * Bn), dim3(64), 0, stream,
                       em, labels, maskp, startT, endT, trans, out);
}